// Round 9
// baseline (635.573 us; speedup 1.0000x reference)
//
#include <hip/hip_runtime.h>

typedef _Float16 half_t;
typedef _Float16 half8  __attribute__((ext_vector_type(8)));
typedef _Float16 half4v __attribute__((ext_vector_type(4)));
typedef float    f32x4  __attribute__((ext_vector_type(4)));

#define ROWB   528          // padded row stride (bytes) for 64-row f16 tiles
#define S_A    0            // x staging
#define S_B    33792        // y staging
#define K1_SMEM 67584
#define K3_SMEM 33792
#define SCALE  0.17677669529663687f

// ---- prep: weights f32->f16 (q_w pre-scaled); fused bias+mask f16 [4][8][64][64]
__global__ __launch_bounds__(256) void swin_prep(
    const float* __restrict__ q_w, const float* __restrict__ kv_w,
    const float* __restrict__ proj_w, const float* __restrict__ rpb,
    const float* __restrict__ mask,
    half_t* __restrict__ w16, half_t* __restrict__ fused)
{
    int t = blockIdx.x * 256 + threadIdx.x;
    if (t < 65536)        w16[t] = (half_t)(q_w[t] * SCALE);
    else if (t < 196608)  w16[t] = (half_t)kv_w[t - 65536];
    else if (t < 262144)  w16[t] = (half_t)proj_w[t - 196608];
    else if (t < 393216) {
        int u = t - 262144;                 // [0, 131072)
        int cls = u >> 15, rest = u & 32767;
        int h = rest >> 12, i = (rest >> 6) & 63, j = rest & 63;
        int idx = ((i >> 3) - (j >> 3) + 7) * 15 + ((i & 7) - (j & 7) + 7);
        int wsel = (cls == 0) ? 0 : (cls == 1) ? 31 : (cls == 2) ? 992 : 1023;
        fused[u] = (half_t)(rpb[idx * 8 + h] + mask[(size_t)wsel * 4096 + i * 64 + j]);
    }
}

static __device__ __forceinline__ unsigned pk2(float a, float b) {
    union { _Float16 h[2]; unsigned u; } t;
    t.h[0] = (_Float16)a; t.h[1] = (_Float16)b; return t.u;
}
static __device__ __forceinline__ half4v h4(float a, float b, float c, float d) {
    half4v v; v[0] = (half_t)a; v[1] = (half_t)b; v[2] = (half_t)c; v[3] = (half_t)d; return v;
}

// C-layout (contraction axis on g*4+r over two 16-tiles) -> A/B-frag (contraction
// axis on g*8+e), l15 axis preserved; verified R2-R7 (output order is natural).
#define BUILD_FRAG(dst, P0, P1)                                          \
    do {                                                                 \
        union { unsigned u[4]; half8 h; } _u;                            \
        _Pragma("unroll")                                                \
        for (int p = 0; p < 4; ++p) {                                    \
            int _src = (p >> 1) ? srcB : srcA;                           \
            unsigned _rlo = (unsigned)__shfl((int)(P0)[p & 1], _src);    \
            unsigned _rhi = (unsigned)__shfl((int)(P1)[p & 1], _src);    \
            _u.u[p] = hi ? _rhi : _rlo;                                  \
        }                                                                \
        dst = _u.h;                                                      \
    } while (0)

// ================= K1: QKV projections (per window) =================
__global__ __launch_bounds__(512, 1) void swin_qkv(
    const float* __restrict__ x, const float* __restrict__ y,
    const float* __restrict__ q_b, const float* __restrict__ kv_b,
    const half_t* __restrict__ w16,
    half_t* __restrict__ Qg, half_t* __restrict__ Kg, half_t* __restrict__ Vtg,
    int b0)
{
    __shared__ __align__(16) char sm[K1_SMEM];
    const int tid  = threadIdx.x;
    const int w    = tid >> 6;
    const int lane = tid & 63;
    const int l15  = lane & 15;
    const int g    = lane >> 4;
    const int bl   = blockIdx.x;
    const int b    = b0 + bl;
    const int jf0  = w * 32;
    const half_t* wkv = w16 + 65536;

    const float* xb = x + (size_t)b * 16384;
    const float* yb = y + (size_t)b * 16384;

    // stage x,y as f16 (verified P0 pattern)
    {
        float4 fx[8], fy[8];
        #pragma unroll
        for (int it = 0; it < 4; ++it) {
            int c = tid + it * 512;
            int row = c >> 5, c8 = c & 31;
            fx[it*2+0] = *(const float4*)(xb + row * 256 + c8 * 8);
            fx[it*2+1] = *(const float4*)(xb + row * 256 + c8 * 8 + 4);
            fy[it*2+0] = *(const float4*)(yb + row * 256 + c8 * 8);
            fy[it*2+1] = *(const float4*)(yb + row * 256 + c8 * 8 + 4);
        }
        #pragma unroll
        for (int it = 0; it < 4; ++it) {
            int c = tid + it * 512;
            int row = c >> 5, c8 = c & 31;
            half8 hx, hy;
            #pragma unroll
            for (int e = 0; e < 4; ++e) {
                hx[e]   = (half_t)(&fx[it*2+0].x)[e];
                hx[e+4] = (half_t)(&fx[it*2+1].x)[e];
                hy[e]   = (half_t)(&fy[it*2+0].x)[e];
                hy[e+4] = (half_t)(&fy[it*2+1].x)[e];
            }
            int off = row * ROWB + c8 * 16;
            *(half8*)(sm + S_A + off) = hx;
            *(half8*)(sm + S_B + off) = hy;
        }
    }
    __syncthreads();

    // Phase A: K^T,V from y (verified)
    f32x4 kacc[2][4], vacc[4][2];
    #pragma unroll
    for (int ft = 0; ft < 2; ++ft)
        #pragma unroll
        for (int tok = 0; tok < 4; ++tok) {
            f32x4 z = {0.f,0.f,0.f,0.f}; kacc[ft][tok] = z; vacc[tok][ft] = z;
        }
    #pragma unroll
    for (int kh = 0; kh < 4; ++kh) {
        half8 wbk[2][2], wbv[2][2];
        #pragma unroll
        for (int k2 = 0; k2 < 2; ++k2) {
            int k0 = (kh * 2 + k2) * 32 + g * 8;
            #pragma unroll
            for (int ft = 0; ft < 2; ++ft) {
                int jf = jf0 + ft * 16 + l15;
                wbk[k2][ft] = *(const half8*)(wkv + jf * 256 + k0);
                wbv[k2][ft] = *(const half8*)(wkv + (256 + jf) * 256 + k0);
            }
        }
        #pragma unroll
        for (int k2 = 0; k2 < 2; ++k2) {
            int k0 = (kh * 2 + k2) * 32 + g * 8;
            half8 a[4];
            #pragma unroll
            for (int tok = 0; tok < 4; ++tok)
                a[tok] = *(const half8*)(sm + S_B + (tok * 16 + l15) * ROWB + k0 * 2);
            #pragma unroll
            for (int ft = 0; ft < 2; ++ft)
                #pragma unroll
                for (int tok = 0; tok < 4; ++tok) {
                    kacc[ft][tok] = __builtin_amdgcn_mfma_f32_16x16x32_f16(wbk[k2][ft], a[tok], kacc[ft][tok], 0, 0, 0);
                    vacc[tok][ft] = __builtin_amdgcn_mfma_f32_16x16x32_f16(a[tok], wbv[k2][ft], vacc[tok][ft], 0, 0, 0);
                }
        }
    }
    // K tok-major [64][256]: token = tok*16+l15, feature = jf0+ft*16+g*4+r
    {
        half_t* Kw = Kg + (size_t)bl * 16384;
        #pragma unroll
        for (int ft = 0; ft < 2; ++ft) {
            float4 kb4 = *(const float4*)(kv_b + jf0 + ft * 16 + g * 4);
            #pragma unroll
            for (int tok = 0; tok < 4; ++tok)
                *(half4v*)(Kw + (tok * 16 + l15) * 256 + jf0 + ft * 16 + g * 4) =
                    h4(kacc[ft][tok][0] + kb4.x, kacc[ft][tok][1] + kb4.y,
                       kacc[ft][tok][2] + kb4.z, kacc[ft][tok][3] + kb4.w);
        }
        // V^T feat-major [256][64]: feature = jf0+ft*16+l15, token = tok*16+g*4+r
        half_t* Vw = Vtg + (size_t)bl * 16384;
        #pragma unroll
        for (int ft = 0; ft < 2; ++ft) {
            float vb = kv_b[256 + jf0 + ft * 16 + l15];
            #pragma unroll
            for (int tok = 0; tok < 4; ++tok)
                *(half4v*)(Vw + (jf0 + ft * 16 + l15) * 64 + tok * 16 + g * 4) =
                    h4(vacc[tok][ft][0] + vb, vacc[tok][ft][1] + vb,
                       vacc[tok][ft][2] + vb, vacc[tok][ft][3] + vb);
    }
    }

    // Phase B: Q^T from x (verified); Q tok-major like K
    {
        f32x4 qacc[2][4];
        #pragma unroll
        for (int ft = 0; ft < 2; ++ft)
            #pragma unroll
            for (int tok = 0; tok < 4; ++tok) { f32x4 z = {0.f,0.f,0.f,0.f}; qacc[ft][tok] = z; }
        #pragma unroll
        for (int kh = 0; kh < 4; ++kh) {
            half8 wbq[2][2];
            #pragma unroll
            for (int k2 = 0; k2 < 2; ++k2) {
                int k0 = (kh * 2 + k2) * 32 + g * 8;
                #pragma unroll
                for (int ft = 0; ft < 2; ++ft)
                    wbq[k2][ft] = *(const half8*)(w16 + (jf0 + ft * 16 + l15) * 256 + k0);
            }
            #pragma unroll
            for (int k2 = 0; k2 < 2; ++k2) {
                int k0 = (kh * 2 + k2) * 32 + g * 8;
                half8 a[4];
                #pragma unroll
                for (int tok = 0; tok < 4; ++tok)
                    a[tok] = *(const half8*)(sm + S_A + (tok * 16 + l15) * ROWB + k0 * 2);
                #pragma unroll
                for (int ft = 0; ft < 2; ++ft)
                    #pragma unroll
                    for (int tok = 0; tok < 4; ++tok)
                        qacc[ft][tok] = __builtin_amdgcn_mfma_f32_16x16x32_f16(wbq[k2][ft], a[tok], qacc[ft][tok], 0, 0, 0);
            }
        }
        half_t* Qw = Qg + (size_t)bl * 16384;
        #pragma unroll
        for (int ft = 0; ft < 2; ++ft) {
            float4 q4 = *(const float4*)(q_b + jf0 + ft * 16 + g * 4);
            #pragma unroll
            for (int tok = 0; tok < 4; ++tok)
                *(half4v*)(Qw + (tok * 16 + l15) * 256 + jf0 + ft * 16 + g * 4) =
                    h4(qacc[ft][tok][0] + q4.x * SCALE, qacc[ft][tok][1] + q4.y * SCALE,
                       qacc[ft][tok][2] + q4.z * SCALE, qacc[ft][tok][3] + q4.w * SCALE);
        }
    }
}

// ================= K2: attention (per window; no LDS, no barriers) =================
__global__ __launch_bounds__(512, 1) void swin_attn(
    const half_t* __restrict__ Qg, const half_t* __restrict__ Kg,
    const half_t* __restrict__ Vtg, const half_t* __restrict__ fused,
    half_t* __restrict__ Og, int b0)
{
    const int tid  = threadIdx.x;
    const int w    = tid >> 6;       // head
    const int lane = tid & 63;
    const int l15  = lane & 15;
    const int g    = lane >> 4;
    const int bl   = blockIdx.x;
    const int b    = b0 + bl;
    const int jf0  = w * 32;
    const int srcA = ((2 * g) & 3) * 16 + l15;
    const int srcB = ((2 * g + 1) & 3) * 16 + l15;
    const int hi   = g >> 1;

    const half_t* Qw = Qg + (size_t)bl * 16384;
    const half_t* Kw = Kg + (size_t)bl * 16384;
    const half_t* Vw = Vtg + (size_t)bl * 16384;

    // frags direct from global (natural order == frag order, verified R2)
    half8 ka[4], qf[4];
    #pragma unroll
    for (int mt = 0; mt < 4; ++mt)
        ka[mt] = *(const half8*)(Kw + (mt * 16 + l15) * 256 + jf0 + g * 8);
    #pragma unroll
    for (int nt = 0; nt < 4; ++nt)
        qf[nt] = *(const half8*)(Qw + (nt * 16 + l15) * 256 + jf0 + g * 8);

    // S^T = K @ Q^T
    f32x4 t[4][4];
    #pragma unroll
    for (int mt = 0; mt < 4; ++mt)
        #pragma unroll
        for (int nt = 0; nt < 4; ++nt) {
            f32x4 z = {0.f,0.f,0.f,0.f};
            t[mt][nt] = __builtin_amdgcn_mfma_f32_16x16x32_f16(ka[mt], qf[nt], z, 0, 0, 0);
        }

    const int wi = b & 1023;
    const int cls = ((((wi >> 5) == 31) ? 2 : 0)) | (((wi & 31) == 31) ? 1 : 0);
    const half_t* fb = fused + ((size_t)cls * 8 + w) * 4096;
    half4v fm[4][4];
    #pragma unroll
    for (int nt = 0; nt < 4; ++nt)
        #pragma unroll
        for (int mt = 0; mt < 4; ++mt)
            fm[nt][mt] = *(const half4v*)(fb + (nt * 16 + l15) * 64 + mt * 16 + g * 4);

    // softmax over j (j = mt*16+g*4+r, i = nt*16+l15)
    #pragma unroll
    for (int nt = 0; nt < 4; ++nt) {
        #pragma unroll
        for (int mt = 0; mt < 4; ++mt)
            #pragma unroll
            for (int r = 0; r < 4; ++r)
                t[mt][nt][r] += (float)fm[nt][mt][r];
        float m = -1e30f;
        #pragma unroll
        for (int mt = 0; mt < 4; ++mt)
            #pragma unroll
            for (int r = 0; r < 4; ++r) m = fmaxf(m, t[mt][nt][r]);
        m = fmaxf(m, __shfl_xor(m, 16));
        m = fmaxf(m, __shfl_xor(m, 32));
        float s = 0.f;
        #pragma unroll
        for (int mt = 0; mt < 4; ++mt)
            #pragma unroll
            for (int r = 0; r < 4; ++r) {
                float p = __expf(t[mt][nt][r] - m);
                t[mt][nt][r] = p;
                s += p;
            }
        s += __shfl_xor(s, 16);
        s += __shfl_xor(s, 32);
        float inv = 1.f / s;
        #pragma unroll
        for (int mt = 0; mt < 4; ++mt)
            #pragma unroll
            for (int r = 0; r < 4; ++r) t[mt][nt][r] *= inv;
    }

    unsigned pp[4][4][2];
    #pragma unroll
    for (int mt = 0; mt < 4; ++mt)
        #pragma unroll
        for (int nt = 0; nt < 4; ++nt) {
            pp[mt][nt][0] = pk2(t[mt][nt][0], t[mt][nt][1]);
            pp[mt][nt][1] = pk2(t[mt][nt][2], t[mt][nt][3]);
        }

    // O^T = V^T @ P^T ; V^T frags direct from global
    f32x4 o[2][4];
    #pragma unroll
    for (int dt = 0; dt < 2; ++dt)
        #pragma unroll
        for (int nt = 0; nt < 4; ++nt) { f32x4 z = {0.f,0.f,0.f,0.f}; o[dt][nt] = z; }
    #pragma unroll
    for (int kc = 0; kc < 2; ++kc) {
        half8 va[2], pf[4];
        #pragma unroll
        for (int dt = 0; dt < 2; ++dt)
            va[dt] = *(const half8*)(Vw + (jf0 + dt * 16 + l15) * 64 + kc * 32 + g * 8);
        #pragma unroll
        for (int nt = 0; nt < 4; ++nt) BUILD_FRAG(pf[nt], pp[kc*2+0][nt], pp[kc*2+1][nt]);
        #pragma unroll
        for (int dt = 0; dt < 2; ++dt)
            #pragma unroll
            for (int nt = 0; nt < 4; ++nt)
                o[dt][nt] = __builtin_amdgcn_mfma_f32_16x16x32_f16(va[dt], pf[nt], o[dt][nt], 0, 0, 0);
    }

    // O tok-major f16 [64][256]: token = nt*16+l15, feature = jf0+dt*16+g*4+r
    half_t* Ow = Og + (size_t)bl * 16384;
    #pragma unroll
    for (int nt = 0; nt < 4; ++nt)
        #pragma unroll
        for (int dt = 0; dt < 2; ++dt)
            *(half4v*)(Ow + (nt * 16 + l15) * 256 + jf0 + dt * 16 + g * 4) =
                h4(o[dt][nt][0], o[dt][nt][1], o[dt][nt][2], o[dt][nt][3]);
}

// ================= K3: output projection (per window) =================
__global__ __launch_bounds__(512, 2) void swin_proj(
    const half_t* __restrict__ Og, const float* __restrict__ proj_b,
    const half_t* __restrict__ w16, float* __restrict__ out, int b0)
{
    __shared__ __align__(16) char sm[K3_SMEM];
    const int tid  = threadIdx.x;
    const int w    = tid >> 6;
    const int lane = tid & 63;
    const int l15  = lane & 15;
    const int g    = lane >> 4;
    const int bl   = blockIdx.x;
    const int b    = b0 + bl;
    const int jf0  = w * 32;
    const half_t* wpj = w16 + 196608;
    const half_t* Ow = Og + (size_t)bl * 16384;

    // stage O (f16 -> LDS, padded rows)
    #pragma unroll
    for (int it = 0; it < 4; ++it) {
        int c = tid + it * 512;
        int row = c >> 5, c8 = c & 31;
        *(half8*)(sm + row * ROWB + c8 * 16) = *(const half8*)(Ow + row * 256 + c8 * 8);
    }
    __syncthreads();

    f32x4 dacc[4][2];
    #pragma unroll
    for (int mt = 0; mt < 4; ++mt)
        #pragma unroll
        for (int ft = 0; ft < 2; ++ft) { f32x4 z = {0.f,0.f,0.f,0.f}; dacc[mt][ft] = z; }
    #pragma unroll
    for (int kh = 0; kh < 4; ++kh) {
        half8 wbp[2][2];
        #pragma unroll
        for (int k2 = 0; k2 < 2; ++k2) {
            int k0 = (kh * 2 + k2) * 32 + g * 8;
            #pragma unroll
            for (int ft = 0; ft < 2; ++ft)
                wbp[k2][ft] = *(const half8*)(wpj + (jf0 + ft * 16 + l15) * 256 + k0);
        }
        #pragma unroll
        for (int k2 = 0; k2 < 2; ++k2) {
            int k0 = (kh * 2 + k2) * 32 + g * 8;
            half8 a[4];
            #pragma unroll
            for (int mt = 0; mt < 4; ++mt)
                a[mt] = *(const half8*)(sm + (mt * 16 + l15) * ROWB + k0 * 2);
            #pragma unroll
            for (int mt = 0; mt < 4; ++mt)
                #pragma unroll
                for (int ft = 0; ft < 2; ++ft)
                    dacc[mt][ft] = __builtin_amdgcn_mfma_f32_16x16x32_f16(wbp[k2][ft], a[mt], dacc[mt][ft], 0, 0, 0);
        }
    }
    float* ob = out + (size_t)b * 16384;
    #pragma unroll
    for (int ft = 0; ft < 2; ++ft) {
        float4 pb4 = *(const float4*)(proj_b + jf0 + ft * 16 + g * 4);
        #pragma unroll
        for (int mt = 0; mt < 4; ++mt) {
            f32x4 v;
            v[0] = dacc[mt][ft][0] + pb4.x;
            v[1] = dacc[mt][ft][1] + pb4.y;
            v[2] = dacc[mt][ft][2] + pb4.z;
            v[3] = dacc[mt][ft][3] + pb4.w;
            *(f32x4*)(ob + (mt * 16 + l15) * 256 + jf0 + ft * 16 + g * 4) = v;
        }
    }
}

extern "C" void kernel_launch(void* const* d_in, const int* in_sizes, int n_in,
                              void* d_out, int out_size, void* d_ws, size_t ws_size,
                              hipStream_t stream) {
    const float* x      = (const float*)d_in[0];
    const float* y      = (const float*)d_in[1];
    const float* mask   = (const float*)d_in[2];
    const float* q_w    = (const float*)d_in[3];
    const float* q_b    = (const float*)d_in[4];
    const float* kv_w   = (const float*)d_in[5];
    const float* kv_b   = (const float*)d_in[6];
    const float* proj_w = (const float*)d_in[7];
    const float* proj_b = (const float*)d_in[8];
    const float* rpb    = (const float*)d_in[9];
    float* out          = (float*)d_out;

    half_t* w16   = (half_t*)d_ws;                       // 512KB
    half_t* fused = (half_t*)((char*)d_ws + 524288);     // 256KB
    const size_t base = 786432;

    // pick chunk count so Q,K,Vt,O intermediates fit in ws (deterministic per ws_size)
    int nchunk = 1;
    while (nchunk < 64) {
        size_t per = (size_t)(4096 / nchunk) * 16384 * 2;   // bytes per buffer
        if (base + 4 * per <= ws_size) break;
        nchunk *= 2;
    }
    const int W = 4096 / nchunk;
    half_t* Qg  = (half_t*)((char*)d_ws + base);
    half_t* Kg  = Qg  + (size_t)W * 16384;
    half_t* Vtg = Kg  + (size_t)W * 16384;
    half_t* Og  = Vtg + (size_t)W * 16384;

    swin_prep<<<1536, 256, 0, stream>>>(q_w, kv_w, proj_w, rpb, mask, w16, fused);
    for (int c = 0; c < nchunk; ++c) {
        int b0 = c * W;
        swin_qkv<<<W, 512, 0, stream>>>(x, y, q_b, kv_b, w16, Qg, Kg, Vtg, b0);
        swin_attn<<<W, 512, 0, stream>>>(Qg, Kg, Vtg, fused, Og, b0);
        swin_proj<<<W, 512, 0, stream>>>(Og, proj_b, w16, out, b0);
    }
}

// Round 10
// 623.343 us; speedup vs baseline: 1.0196x; 1.0196x over previous
//
#include <hip/hip_runtime.h>

typedef _Float16 half_t;
typedef _Float16 half8  __attribute__((ext_vector_type(8)));
typedef _Float16 half4v __attribute__((ext_vector_type(4)));
typedef float    f32x4  __attribute__((ext_vector_type(4)));

#define ROWB   528          // padded row stride (bytes) for 64x256 f16 staging tiles
#define S_A    0            // x staging
#define S_B    33792        // y staging
#define K1_SMEM 67584
#define SCALE  0.17677669529663687f

#define BAR() do { \
    asm volatile("s_waitcnt lgkmcnt(0)" ::: "memory"); \
    __builtin_amdgcn_s_barrier(); \
    __builtin_amdgcn_sched_barrier(0); \
} while (0)

// ---- prep: weights f32->f16 (q_w pre-scaled); fused bias+mask in FRAG-MAJOR order:
// fusedF[cls][head][(nt*4+mt)*256 + lane*4 + r] = bias+mask at i=nt*16+l15, j=mt*16+g*4+r
__global__ __launch_bounds__(256) void swin_prep(
    const float* __restrict__ q_w, const float* __restrict__ kv_w,
    const float* __restrict__ proj_w, const float* __restrict__ rpb,
    const float* __restrict__ mask,
    half_t* __restrict__ w16, half_t* __restrict__ fusedF)
{
    int t = blockIdx.x * 256 + threadIdx.x;
    if (t < 65536)        w16[t] = (half_t)(q_w[t] * SCALE);
    else if (t < 196608)  w16[t] = (half_t)kv_w[t - 65536];
    else if (t < 262144)  w16[t] = (half_t)proj_w[t - 196608];
    else if (t < 393216) {
        int u = t - 262144;                 // [0, 131072)
        int cls = u >> 15, q = u & 32767;
        int h = q >> 12, s = q & 4095;
        int nt = s >> 10, mt = (s >> 8) & 3, lane = (s >> 2) & 63, r = s & 3;
        int g = lane >> 4, l15 = lane & 15;
        int i = nt * 16 + l15, j = mt * 16 + g * 4 + r;
        int idx = ((i >> 3) - (j >> 3) + 7) * 15 + ((i & 7) - (j & 7) + 7);
        int wsel = (cls == 0) ? 0 : (cls == 1) ? 31 : (cls == 2) ? 992 : 1023;
        fusedF[u] = (half_t)(rpb[idx * 8 + h] + mask[(size_t)wsel * 4096 + i * 64 + j]);
    }
}

static __device__ __forceinline__ unsigned pk2(float a, float b) {
    union { _Float16 h[2]; unsigned u; } t;
    t.h[0] = (_Float16)a; t.h[1] = (_Float16)b; return t.u;
}

// C-layout (contraction axis on g*4+r over two 16-tiles) -> A/B-frag (contraction
// axis on g*8+e), l15 axis preserved; verified R2-R9.
#define BUILD_FRAG(dst, P0, P1)                                          \
    do {                                                                 \
        union { unsigned u[4]; half8 h; } _u;                            \
        _Pragma("unroll")                                                \
        for (int p = 0; p < 4; ++p) {                                    \
            int _src = (p >> 1) ? srcB : srcA;                           \
            unsigned _rlo = (unsigned)__shfl((int)(P0)[p & 1], _src);    \
            unsigned _rhi = (unsigned)__shfl((int)(P1)[p & 1], _src);    \
            _u.u[p] = hi ? _rhi : _rlo;                                  \
        }                                                                \
        dst = _u.h;                                                      \
    } while (0)

// ================= K1: persistent pipelined QKV =================
// Intermediates in frag-major layout: buf[winInChunk][head][slot][lane] (half8 per lane)
// K: slot=mt(token tile); Q: slot=nt; Vt: slot=kc*2+dt.
__global__ __launch_bounds__(512, 1) void swin_qkv(
    const float* __restrict__ x, const float* __restrict__ y,
    const float* __restrict__ q_b, const float* __restrict__ kv_b,
    const half_t* __restrict__ w16,
    half_t* __restrict__ Qg, half_t* __restrict__ Kg, half_t* __restrict__ Vtg,
    int b0, int nw)
{
    __shared__ __align__(16) char sm[K1_SMEM];
    const int tid  = threadIdx.x;
    const int w    = tid >> 6;
    const int lane = tid & 63;
    const int l15  = lane & 15;
    const int g    = lane >> 4;
    const int jf0  = w * 32;
    const int srcA = ((2 * g) & 3) * 16 + l15;
    const int srcB = ((2 * g + 1) & 3) * 16 + l15;
    const int hi   = g >> 1;
    const half_t* wkv = w16 + 65536;

    // hoisted biases
    float4 kb4[2], qb4s[2];
    float  vb[2];
    #pragma unroll
    for (int ft = 0; ft < 2; ++ft) {
        kb4[ft] = *(const float4*)(kv_b + jf0 + ft * 16 + g * 4);
        float4 q4 = *(const float4*)(q_b + jf0 + ft * 16 + g * 4);
        qb4s[ft].x = q4.x * SCALE; qb4s[ft].y = q4.y * SCALE;
        qb4s[ft].z = q4.z * SCALE; qb4s[ft].w = q4.w * SCALE;
        vb[ft] = kv_b[256 + jf0 + ft * 16 + l15];
    }

    const int c0 = tid, rw0 = c0 >> 5, cc0 = c0 & 31;    // staging chunk geometry
    float4 fx[8], fy[8];

    // prologue: issue window-0 loads
    {
        int b = b0 + blockIdx.x * nw;
        const float* xb = x + (size_t)b * 16384;
        const float* yb = y + (size_t)b * 16384;
        #pragma unroll
        for (int it = 0; it < 4; ++it) {
            int row = rw0 + it * 16;
            fx[it*2+0] = *(const float4*)(xb + row * 256 + cc0 * 8);
            fx[it*2+1] = *(const float4*)(xb + row * 256 + cc0 * 8 + 4);
            fy[it*2+0] = *(const float4*)(yb + row * 256 + cc0 * 8);
            fy[it*2+1] = *(const float4*)(yb + row * 256 + cc0 * 8 + 4);
        }
    }

    for (int wd = 0; wd < nw; ++wd) {
        const int bl = blockIdx.x * nw + wd;    // window within chunk

        // ---- convert + stage current window (waits on fx/fy issued last iter) ----
        #pragma unroll
        for (int it = 0; it < 4; ++it) {
            int row = rw0 + it * 16;
            half8 hx, hy;
            #pragma unroll
            for (int e = 0; e < 4; ++e) {
                hx[e]   = (half_t)(&fx[it*2+0].x)[e];
                hx[e+4] = (half_t)(&fx[it*2+1].x)[e];
                hy[e]   = (half_t)(&fy[it*2+0].x)[e];
                hy[e+4] = (half_t)(&fy[it*2+1].x)[e];
            }
            int off = row * ROWB + cc0 * 16;
            *(half8*)(sm + S_A + off) = hx;
            *(half8*)(sm + S_B + off) = hy;
        }

        // ---- issue next window's loads (fly during compute below) ----
        if (wd + 1 < nw) {
            int bn = b0 + blockIdx.x * nw + wd + 1;
            const float* xb = x + (size_t)bn * 16384;
            const float* yb = y + (size_t)bn * 16384;
            #pragma unroll
            for (int it = 0; it < 4; ++it) {
                int row = rw0 + it * 16;
                fx[it*2+0] = *(const float4*)(xb + row * 256 + cc0 * 8);
                fx[it*2+1] = *(const float4*)(xb + row * 256 + cc0 * 8 + 4);
                fy[it*2+0] = *(const float4*)(yb + row * 256 + cc0 * 8);
                fy[it*2+1] = *(const float4*)(yb + row * 256 + cc0 * 8 + 4);
            }
        }

        BAR();   // staging visible

        // ---- Phase A: K^T,V from y (reads S_B) ----
        f32x4 kacc[2][4], vacc[4][2];
        #pragma unroll
        for (int ft = 0; ft < 2; ++ft)
            #pragma unroll
            for (int tok = 0; tok < 4; ++tok) {
                f32x4 z = {0.f,0.f,0.f,0.f}; kacc[ft][tok] = z; vacc[tok][ft] = z;
            }
        #pragma unroll
        for (int kh = 0; kh < 4; ++kh) {
            half8 wbk[2][2], wbv[2][2];
            #pragma unroll
            for (int k2 = 0; k2 < 2; ++k2) {
                int k0 = (kh * 2 + k2) * 32 + g * 8;
                #pragma unroll
                for (int ft = 0; ft < 2; ++ft) {
                    int jf = jf0 + ft * 16 + l15;
                    wbk[k2][ft] = *(const half8*)(wkv + jf * 256 + k0);
                    wbv[k2][ft] = *(const half8*)(wkv + (256 + jf) * 256 + k0);
                }
            }
            #pragma unroll
            for (int k2 = 0; k2 < 2; ++k2) {
                int k0 = (kh * 2 + k2) * 32 + g * 8;
                half8 a[4];
                #pragma unroll
                for (int tok = 0; tok < 4; ++tok)
                    a[tok] = *(const half8*)(sm + S_B + (tok * 16 + l15) * ROWB + k0 * 2);
                #pragma unroll
                for (int ft = 0; ft < 2; ++ft)
                    #pragma unroll
                    for (int tok = 0; tok < 4; ++tok) {
                        kacc[ft][tok] = __builtin_amdgcn_mfma_f32_16x16x32_f16(wbk[k2][ft], a[tok], kacc[ft][tok], 0, 0, 0);
                        vacc[tok][ft] = __builtin_amdgcn_mfma_f32_16x16x32_f16(a[tok], wbv[k2][ft], vacc[tok][ft], 0, 0, 0);
                    }
            }
        }
        // pack K^T (+bias) and V (+bias)
        unsigned kp[2][4][2], vp[4][2][2];
        #pragma unroll
        for (int ft = 0; ft < 2; ++ft)
            #pragma unroll
            for (int tok = 0; tok < 4; ++tok) {
                kp[ft][tok][0] = pk2(kacc[ft][tok][0] + kb4[ft].x, kacc[ft][tok][1] + kb4[ft].y);
                kp[ft][tok][1] = pk2(kacc[ft][tok][2] + kb4[ft].z, kacc[ft][tok][3] + kb4[ft].w);
                vp[tok][ft][0] = pk2(vacc[tok][ft][0] + vb[ft], vacc[tok][ft][1] + vb[ft]);
                vp[tok][ft][1] = pk2(vacc[tok][ft][2] + vb[ft], vacc[tok][ft][3] + vb[ft]);
            }

        // ---- Phase B: Q^T from x (reads S_A) ----
        unsigned qp[2][4][2];
        {
            f32x4 qacc[2][4];
            #pragma unroll
            for (int ft = 0; ft < 2; ++ft)
                #pragma unroll
                for (int tok = 0; tok < 4; ++tok) { f32x4 z = {0.f,0.f,0.f,0.f}; qacc[ft][tok] = z; }
            #pragma unroll
            for (int kh = 0; kh < 4; ++kh) {
                half8 wbq[2][2];
                #pragma unroll
                for (int k2 = 0; k2 < 2; ++k2) {
                    int k0 = (kh * 2 + k2) * 32 + g * 8;
                    #pragma unroll
                    for (int ft = 0; ft < 2; ++ft)
                        wbq[k2][ft] = *(const half8*)(w16 + (jf0 + ft * 16 + l15) * 256 + k0);
                }
                #pragma unroll
                for (int k2 = 0; k2 < 2; ++k2) {
                    int k0 = (kh * 2 + k2) * 32 + g * 8;
                    half8 a[4];
                    #pragma unroll
                    for (int tok = 0; tok < 4; ++tok)
                        a[tok] = *(const half8*)(sm + S_A + (tok * 16 + l15) * ROWB + k0 * 2);
                    #pragma unroll
                    for (int ft = 0; ft < 2; ++ft)
                        #pragma unroll
                        for (int tok = 0; tok < 4; ++tok)
                            qacc[ft][tok] = __builtin_amdgcn_mfma_f32_16x16x32_f16(wbq[k2][ft], a[tok], qacc[ft][tok], 0, 0, 0);
                }
            }
            #pragma unroll
            for (int ft = 0; ft < 2; ++ft)
                #pragma unroll
                for (int tok = 0; tok < 4; ++tok) {
                    qp[ft][tok][0] = pk2(qacc[ft][tok][0] + qb4s[ft].x, qacc[ft][tok][1] + qb4s[ft].y);
                    qp[ft][tok][1] = pk2(qacc[ft][tok][2] + qb4s[ft].z, qacc[ft][tok][3] + qb4s[ft].w);
                }
        }

        // ---- epilogue: build frags (verified shuffles) + COALESCED frag-major stores ----
        {
            half_t* Kw = Kg  + (size_t)bl * 16384;
            half_t* Qw = Qg  + (size_t)bl * 16384;
            half_t* Vw = Vtg + (size_t)bl * 16384;
            #pragma unroll
            for (int mt = 0; mt < 4; ++mt) {
                half8 f;
                BUILD_FRAG(f, kp[0][mt], kp[1][mt]);
                *(half8*)(Kw + (w * 4 + mt) * 512 + lane * 8) = f;
            }
            #pragma unroll
            for (int nt = 0; nt < 4; ++nt) {
                half8 f;
                BUILD_FRAG(f, qp[0][nt], qp[1][nt]);
                *(half8*)(Qw + (w * 4 + nt) * 512 + lane * 8) = f;
            }
            #pragma unroll
            for (int kc = 0; kc < 2; ++kc)
                #pragma unroll
                for (int dt = 0; dt < 2; ++dt) {
                    half8 f;
                    BUILD_FRAG(f, vp[kc*2+0][dt], vp[kc*2+1][dt]);
                    *(half8*)(Vw + (w * 4 + kc * 2 + dt) * 512 + lane * 8) = f;
                }
        }

        BAR();   // all LDS reads of this window done -> next iter may overwrite staging
    }
}

// ================= K2: attention (no LDS; fully coalesced frag loads/stores) =================
__global__ __launch_bounds__(512, 1) void swin_attn(
    const half_t* __restrict__ Qg, const half_t* __restrict__ Kg,
    const half_t* __restrict__ Vtg, const half_t* __restrict__ fusedF,
    half_t* __restrict__ Og, int b0)
{
    const int tid  = threadIdx.x;
    const int w    = tid >> 6;       // head
    const int lane = tid & 63;
    const int l15  = lane & 15;
    const int g    = lane >> 4;
    const int bl   = blockIdx.x;
    const int b    = b0 + bl;
    const int srcA = ((2 * g) & 3) * 16 + l15;
    const int srcB = ((2 * g + 1) & 3) * 16 + l15;
    const int hi   = g >> 1;

    const half_t* Qw = Qg  + (size_t)bl * 16384;
    const half_t* Kw = Kg  + (size_t)bl * 16384;
    const half_t* Vw = Vtg + (size_t)bl * 16384;

    // coalesced frag loads
    half8 ka[4], qf[4];
    #pragma unroll
    for (int mt = 0; mt < 4; ++mt)
        ka[mt] = *(const half8*)(Kw + (w * 4 + mt) * 512 + lane * 8);
    #pragma unroll
    for (int nt = 0; nt < 4; ++nt)
        qf[nt] = *(const half8*)(Qw + (w * 4 + nt) * 512 + lane * 8);

    // S^T = K @ Q^T
    f32x4 t[4][4];
    #pragma unroll
    for (int mt = 0; mt < 4; ++mt)
        #pragma unroll
        for (int nt = 0; nt < 4; ++nt) {
            f32x4 z = {0.f,0.f,0.f,0.f};
            t[mt][nt] = __builtin_amdgcn_mfma_f32_16x16x32_f16(ka[mt], qf[nt], z, 0, 0, 0);
        }

    const int wi = b & 1023;
    const int cls = ((((wi >> 5) == 31) ? 2 : 0)) | (((wi & 31) == 31) ? 1 : 0);
    const half_t* fb = fusedF + ((size_t)cls * 8 + w) * 4096;
    half4v fm[4][4];   // [nt][mt], coalesced 8B/lane
    #pragma unroll
    for (int nt = 0; nt < 4; ++nt)
        #pragma unroll
        for (int mt = 0; mt < 4; ++mt)
            fm[nt][mt] = *(const half4v*)(fb + (nt * 4 + mt) * 256 + lane * 4);

    // softmax over j (j = mt*16+g*4+r, i = nt*16+l15)
    #pragma unroll
    for (int nt = 0; nt < 4; ++nt) {
        #pragma unroll
        for (int mt = 0; mt < 4; ++mt)
            #pragma unroll
            for (int r = 0; r < 4; ++r)
                t[mt][nt][r] += (float)fm[nt][mt][r];
        float m = -1e30f;
        #pragma unroll
        for (int mt = 0; mt < 4; ++mt)
            #pragma unroll
            for (int r = 0; r < 4; ++r) m = fmaxf(m, t[mt][nt][r]);
        m = fmaxf(m, __shfl_xor(m, 16));
        m = fmaxf(m, __shfl_xor(m, 32));
        float s = 0.f;
        #pragma unroll
        for (int mt = 0; mt < 4; ++mt)
            #pragma unroll
            for (int r = 0; r < 4; ++r) {
                float p = __expf(t[mt][nt][r] - m);
                t[mt][nt][r] = p;
                s += p;
            }
        s += __shfl_xor(s, 16);
        s += __shfl_xor(s, 32);
        float inv = 1.f / s;
        #pragma unroll
        for (int mt = 0; mt < 4; ++mt)
            #pragma unroll
            for (int r = 0; r < 4; ++r) t[mt][nt][r] *= inv;
    }

    unsigned pp[4][4][2];
    #pragma unroll
    for (int mt = 0; mt < 4; ++mt)
        #pragma unroll
        for (int nt = 0; nt < 4; ++nt) {
            pp[mt][nt][0] = pk2(t[mt][nt][0], t[mt][nt][1]);
            pp[mt][nt][1] = pk2(t[mt][nt][2], t[mt][nt][3]);
        }

    // O^T = V^T @ P^T
    f32x4 o[2][4];
    #pragma unroll
    for (int dt = 0; dt < 2; ++dt)
        #pragma unroll
        for (int nt = 0; nt < 4; ++nt) { f32x4 z = {0.f,0.f,0.f,0.f}; o[dt][nt] = z; }
    #pragma unroll
    for (int kc = 0; kc < 2; ++kc) {
        half8 va[2], pf[4];
        #pragma unroll
        for (int dt = 0; dt < 2; ++dt)
            va[dt] = *(const half8*)(Vw + (w * 4 + kc * 2 + dt) * 512 + lane * 8);
        #pragma unroll
        for (int nt = 0; nt < 4; ++nt) BUILD_FRAG(pf[nt], pp[kc*2+0][nt], pp[kc*2+1][nt]);
        #pragma unroll
        for (int dt = 0; dt < 2; ++dt)
            #pragma unroll
            for (int nt = 0; nt < 4; ++nt)
                o[dt][nt] = __builtin_amdgcn_mfma_f32_16x16x32_f16(va[dt], pf[nt], o[dt][nt], 0, 0, 0);
    }

    // O -> frag-major coalesced store: slot = nt (token tile), contraction axis = feature
    unsigned po[2][4][2];
    #pragma unroll
    for (int dt = 0; dt < 2; ++dt)
        #pragma unroll
        for (int nt = 0; nt < 4; ++nt) {
            po[dt][nt][0] = pk2(o[dt][nt][0], o[dt][nt][1]);
            po[dt][nt][1] = pk2(o[dt][nt][2], o[dt][nt][3]);
        }
    half_t* Ow = Og + (size_t)bl * 16384;
    #pragma unroll
    for (int nt = 0; nt < 4; ++nt) {
        half8 f;
        BUILD_FRAG(f, po[0][nt], po[1][nt]);
        *(half8*)(Ow + (w * 4 + nt) * 512 + lane * 8) = f;
    }
}

// ================= K3: output projection (coalesced O reads; LDS-transposed f32 out) =================
__global__ __launch_bounds__(512, 2) void swin_proj(
    const half_t* __restrict__ Og, const float* __restrict__ proj_b,
    const half_t* __restrict__ w16, float* __restrict__ out, int b0)
{
    __shared__ __align__(16) float T[64 * 260];   // 66560 B
    const int tid  = threadIdx.x;
    const int w    = tid >> 6;
    const int lane = tid & 63;
    const int l15  = lane & 15;
    const int g    = lane >> 4;
    const int bl   = blockIdx.x;
    const int b    = b0 + bl;
    const int jf0  = w * 32;
    const half_t* wpj = w16 + 196608;
    const half_t* Ow = Og + (size_t)bl * 16384;

    f32x4 dacc[4][2];
    #pragma unroll
    for (int mt = 0; mt < 4; ++mt)
        #pragma unroll
        for (int ft = 0; ft < 2; ++ft) { f32x4 z = {0.f,0.f,0.f,0.f}; dacc[mt][ft] = z; }
    #pragma unroll
    for (int kh = 0; kh < 4; ++kh) {
        half8 wbp[2][2];
        #pragma unroll
        for (int k2 = 0; k2 < 2; ++k2) {
            int k0 = (kh * 2 + k2) * 32 + g * 8;
            #pragma unroll
            for (int ft = 0; ft < 2; ++ft)
                wbp[k2][ft] = *(const half8*)(wpj + (jf0 + ft * 16 + l15) * 256 + k0);
        }
        #pragma unroll
        for (int k2 = 0; k2 < 2; ++k2) {
            int hc = kh * 2 + k2;     // contraction head chunk
            half8 a[4];
            #pragma unroll
            for (int mt = 0; mt < 4; ++mt)
                a[mt] = *(const half8*)(Ow + (hc * 4 + mt) * 512 + lane * 8);
            #pragma unroll
            for (int mt = 0; mt < 4; ++mt)
                #pragma unroll
                for (int ft = 0; ft < 2; ++ft)
                    dacc[mt][ft] = __builtin_amdgcn_mfma_f32_16x16x32_f16(wbp[k2][ft], a[mt], dacc[mt][ft], 0, 0, 0);
        }
    }
    // transpose via LDS: token on l15, feature on g*4+r -> row-major [64][256]
    #pragma unroll
    for (int ft = 0; ft < 2; ++ft) {
        float4 pb4 = *(const float4*)(proj_b + jf0 + ft * 16 + g * 4);
        #pragma unroll
        for (int mt = 0; mt < 4; ++mt) {
            f32x4 v;
            v[0] = dacc[mt][ft][0] + pb4.x;
            v[1] = dacc[mt][ft][1] + pb4.y;
            v[2] = dacc[mt][ft][2] + pb4.z;
            v[3] = dacc[mt][ft][3] + pb4.w;
            *(f32x4*)(T + (mt * 16 + l15) * 260 + jf0 + ft * 16 + g * 4) = v;
        }
    }
    __syncthreads();
    float* ob = out + (size_t)b * 16384;
    #pragma unroll
    for (int it = 0; it < 8; ++it) {
        int c = tid + it * 512;          // 4096 chunks of f32x4
        int tok = c >> 6, f4 = c & 63;
        *(f32x4*)(ob + tok * 256 + f4 * 4) = *(const f32x4*)(T + tok * 260 + f4 * 4);
    }
}

extern "C" void kernel_launch(void* const* d_in, const int* in_sizes, int n_in,
                              void* d_out, int out_size, void* d_ws, size_t ws_size,
                              hipStream_t stream) {
    const float* x      = (const float*)d_in[0];
    const float* y      = (const float*)d_in[1];
    const float* mask   = (const float*)d_in[2];
    const float* q_w    = (const float*)d_in[3];
    const float* q_b    = (const float*)d_in[4];
    const float* kv_w   = (const float*)d_in[5];
    const float* kv_b   = (const float*)d_in[6];
    const float* proj_w = (const float*)d_in[7];
    const float* proj_b = (const float*)d_in[8];
    const float* rpb    = (const float*)d_in[9];
    float* out          = (float*)d_out;

    half_t* w16    = (half_t*)d_ws;                      // 512KB
    half_t* fusedF = (half_t*)((char*)d_ws + 524288);    // 256KB
    const size_t base = 786432;

    int nchunk = 1;
    while (nchunk < 64) {
        size_t per = (size_t)(4096 / nchunk) * 16384 * 2;
        if (base + 4 * per <= ws_size) break;
        nchunk *= 2;
    }
    const int W = 4096 / nchunk;
    half_t* Qg  = (half_t*)((char*)d_ws + base);
    half_t* Kg  = Qg  + (size_t)W * 16384;
    half_t* Vtg = Kg  + (size_t)W * 16384;
    half_t* Og  = Vtg + (size_t)W * 16384;

    const int g1 = (W < 256) ? W : 256;
    const int nw = W / g1;

    swin_prep<<<1536, 256, 0, stream>>>(q_w, kv_w, proj_w, rpb, mask, w16, fusedF);
    for (int c = 0; c < nchunk; ++c) {
        int b0 = c * W;
        swin_qkv<<<g1, 512, 0, stream>>>(x, y, q_b, kv_b, w16, Qg, Kg, Vtg, b0, nw);
        swin_attn<<<W, 512, 0, stream>>>(Qg, Kg, Vtg, fusedF, Og, b0);
        swin_proj<<<W, 512, 0, stream>>>(Og, proj_b, w16, out, b0);
    }
}